// Round 12
// baseline (85.741 us; speedup 1.0000x reference)
//
#include <hip/hip_runtime.h>
#include <math.h>

#define TB 2048
#define TK 128
#define TD 512
#define BR 32            // rows per main-kernel block
#define NBLK (TB / BR)   // 64
#define KAUG 1024        // augmented K' = 2*TD
#define KC 128           // K' per chunk
#define NCH 8
#define XSTR 136         // f16 row stride (128 data + 8 pad) = 272 B

typedef _Float16 half8 __attribute__((ext_vector_type(8)));
typedef float f32x4 __attribute__((ext_vector_type(4)));

// ws layout: Wt f16[128][1024] (256 KB) ; off f32[128] ; ebuf f32[128]

// ---------------------------------------------------------------------------
// Prep: per class k build the f16 B-matrix row Wt[k][k'] with chunked layout
//   k' = c*128 + dd      -> 1/a            (d = c*64 + dd, a = |D|+eps)
//   k' = c*128 + 64 + dd -> -2c/a
// plus off[k] = -0.5*(e_k + sum log a), ebuf[k] = e_k = sum c^2/a.
// ---------------------------------------------------------------------------
__global__ __launch_bounds__(64) void prep_kernel(const float* __restrict__ C,
        const float* __restrict__ Dm, _Float16* __restrict__ Wt,
        float* __restrict__ off, float* __restrict__ ebuf) {
    const int k = blockIdx.x, lane = threadIdx.x;
    float esum = 0.f, lsum = 0.f;
    #pragma unroll
    for (int i = 0; i < 8; ++i) {
        int d = i * 64 + lane;
        float a = fabsf(Dm[k * TD + d]) + 1e-8f;
        float ia = 1.0f / a;
        float c = C[k * TD + d];
        float cia = c * ia;
        esum += c * cia;
        lsum += logf(a);
        Wt[(size_t)k * KAUG + i * KC + lane] = (_Float16)ia;
        Wt[(size_t)k * KAUG + i * KC + 64 + lane] = (_Float16)(-2.0f * cia);
    }
    #pragma unroll
    for (int m = 32; m >= 1; m >>= 1) {
        esum += __shfl_xor(esum, m, 64);
        lsum += __shfl_xor(lsum, m, 64);
    }
    if (lane == 0) { off[k] = -0.5f * (esum + lsum); ebuf[k] = esum; }
}

__device__ inline half8 sq8(float4 a, float4 b) {
    half8 h;
    h[0] = (_Float16)(a.x * a.x); h[1] = (_Float16)(a.y * a.y);
    h[2] = (_Float16)(a.z * a.z); h[3] = (_Float16)(a.w * a.w);
    h[4] = (_Float16)(b.x * b.x); h[5] = (_Float16)(b.y * b.y);
    h[6] = (_Float16)(b.z * b.z); h[7] = (_Float16)(b.w * b.w);
    return h;
}
__device__ inline half8 id8(float4 a, float4 b) {
    half8 h;
    h[0] = (_Float16)a.x; h[1] = (_Float16)a.y;
    h[2] = (_Float16)a.z; h[3] = (_Float16)a.w;
    h[4] = (_Float16)b.x; h[5] = (_Float16)b.y;
    h[6] = (_Float16)b.z; h[7] = (_Float16)b.w;
    return h;
}

// ---------------------------------------------------------------------------
// Main: 64 blocks x 128 thr (2 waves). Block = 32 rows x 128 k, K'=1024 in 8
// chunks. Wave w owns cols [w*64, w*64+64): 2 row-tiles x 4 n-tiles of
// mfma_f32_16x16x32_f16. Epilogue: in-block softmax + argmax + dist.
// ---------------------------------------------------------------------------
__global__ __launch_bounds__(128) void gmm_kernel(const float* __restrict__ x,
        const _Float16* __restrict__ Wt, const float* __restrict__ off,
        const float* __restrict__ ebuf, float* __restrict__ out) {
    __shared__ _Float16 XA[BR][XSTR];   // 8.7 KB  [row][k'_chunk]
    __shared__ _Float16 WB[TK][XSTR];   // 34.8 KB [col][k'_chunk]
    __shared__ float red_m[2][BR], red_s[2][BR], red_bv[2][BR], red_bg[2][BR];
    __shared__ int red_bi[2][BR];

    const int tid = threadIdx.x;
    const int l = tid & 63;
    const int w = tid >> 6;
    const int b0 = blockIdx.x * BR;
    const int l15 = l & 15;
    const int lg = l >> 4;

    f32x4 acc[2][4];
    #pragma unroll
    for (int i = 0; i < 2; ++i)
        #pragma unroll
        for (int j = 0; j < 4; ++j) acc[i][j] = (f32x4){0.f, 0.f, 0.f, 0.f};

    float4 xg[2][2];
    uint4 wg[16];

#define LOADX(c_) { \
    _Pragma("unroll") for (int i = 0; i < 2; ++i) { \
        int f = tid + i * 128; int row = f >> 3; int g = f & 7; \
        const float4* src = reinterpret_cast<const float4*>( \
            &x[(size_t)(b0 + row) * TD + (c_) * 64 + g * 8]); \
        xg[i][0] = src[0]; xg[i][1] = src[1]; } \
    _Pragma("unroll") for (int i = 0; i < 16; ++i) { \
        int f = tid + i * 128; int col = f >> 4; int bb = f & 15; \
        wg[i] = *reinterpret_cast<const uint4*>( \
            &Wt[(size_t)col * KAUG + (c_) * KC + bb * 8]); } }

#define STORELDS() { \
    _Pragma("unroll") for (int i = 0; i < 2; ++i) { \
        int f = tid + i * 128; int row = f >> 3; int g = f & 7; \
        *reinterpret_cast<half8*>(&XA[row][g * 8])      = sq8(xg[i][0], xg[i][1]); \
        *reinterpret_cast<half8*>(&XA[row][64 + g * 8]) = id8(xg[i][0], xg[i][1]); } \
    _Pragma("unroll") for (int i = 0; i < 16; ++i) { \
        int f = tid + i * 128; int col = f >> 4; int bb = f & 15; \
        *reinterpret_cast<uint4*>(&WB[col][bb * 8]) = wg[i]; } }

#define COMPUTE() { \
    _Pragma("unroll") for (int ks = 0; ks < 4; ++ks) { \
        const int ko = ks * 32 + lg * 8; \
        half8 a0 = *reinterpret_cast<const half8*>(&XA[l15][ko]); \
        half8 a1 = *reinterpret_cast<const half8*>(&XA[16 + l15][ko]); \
        half8 q0 = *reinterpret_cast<const half8*>(&WB[w * 64 + l15][ko]); \
        half8 q1 = *reinterpret_cast<const half8*>(&WB[w * 64 + 16 + l15][ko]); \
        half8 q2 = *reinterpret_cast<const half8*>(&WB[w * 64 + 32 + l15][ko]); \
        half8 q3 = *reinterpret_cast<const half8*>(&WB[w * 64 + 48 + l15][ko]); \
        acc[0][0] = __builtin_amdgcn_mfma_f32_16x16x32_f16(a0, q0, acc[0][0], 0, 0, 0); \
        acc[0][1] = __builtin_amdgcn_mfma_f32_16x16x32_f16(a0, q1, acc[0][1], 0, 0, 0); \
        acc[0][2] = __builtin_amdgcn_mfma_f32_16x16x32_f16(a0, q2, acc[0][2], 0, 0, 0); \
        acc[0][3] = __builtin_amdgcn_mfma_f32_16x16x32_f16(a0, q3, acc[0][3], 0, 0, 0); \
        acc[1][0] = __builtin_amdgcn_mfma_f32_16x16x32_f16(a1, q0, acc[1][0], 0, 0, 0); \
        acc[1][1] = __builtin_amdgcn_mfma_f32_16x16x32_f16(a1, q1, acc[1][1], 0, 0, 0); \
        acc[1][2] = __builtin_amdgcn_mfma_f32_16x16x32_f16(a1, q2, acc[1][2], 0, 0, 0); \
        acc[1][3] = __builtin_amdgcn_mfma_f32_16x16x32_f16(a1, q3, acc[1][3], 0, 0, 0); } }

    LOADX(0)
    STORELDS()
    __syncthreads();
    for (int c = 0; c < NCH; ++c) {
        if (c == 0) { LOADX(1) } else if (c == 1) { LOADX(2) }
        else if (c == 2) { LOADX(3) } else if (c == 3) { LOADX(4) }
        else if (c == 4) { LOADX(5) } else if (c == 5) { LOADX(6) }
        else if (c == 6) { LOADX(7) }
        COMPUTE()
        if (c < NCH - 1) {
            __syncthreads();   // compute done (WAR)
            STORELDS()
            __syncthreads();   // stores visible
        }
    }
#undef LOADX
#undef STORELDS
#undef COMPUTE

    // ---------------- epilogue: softmax over k, argmax + dist ----------------
    float offc[4], ec_[4];
    #pragma unroll
    for (int nt = 0; nt < 4; ++nt) {
        int col = w * 64 + nt * 16 + l15;
        offc[nt] = off[col];
        ec_[nt] = ebuf[col];
    }
    (void)ec_;

    // s[rt][nt][e]: row = rt*16 + lg*4 + e, col = w*64 + nt*16 + l15  (m89 C/D)
    float sv[2][4][4];
    #pragma unroll
    for (int rt = 0; rt < 2; ++rt)
        #pragma unroll
        for (int nt = 0; nt < 4; ++nt)
            #pragma unroll
            for (int e = 0; e < 4; ++e)
                sv[rt][nt][e] = fmaf(-0.5f, acc[rt][nt][e], offc[nt]);

    // pass 1: per-row argmax (val, idx, gemm) over nt then over 16 col-lanes
    float bv[2][4], bg[2][4]; int bi[2][4];
    #pragma unroll
    for (int rt = 0; rt < 2; ++rt)
        #pragma unroll
        for (int e = 0; e < 4; ++e) {
            float v = sv[rt][0][e]; int idx = w * 64 + l15; float g = acc[rt][0][e];
            #pragma unroll
            for (int nt = 1; nt < 4; ++nt) {
                float v2 = sv[rt][nt][e]; int i2 = w * 64 + nt * 16 + l15;
                if (v2 > v) { v = v2; idx = i2; g = acc[rt][nt][e]; }
            }
            bv[rt][e] = v; bi[rt][e] = idx; bg[rt][e] = g;
        }
    #pragma unroll
    for (int msk = 1; msk <= 8; msk <<= 1) {
        #pragma unroll
        for (int rt = 0; rt < 2; ++rt)
            #pragma unroll
            for (int e = 0; e < 4; ++e) {
                float ov = __shfl_xor(bv[rt][e], msk, 64);
                int oi = __shfl_xor(bi[rt][e], msk, 64);
                float og = __shfl_xor(bg[rt][e], msk, 64);
                if (ov > bv[rt][e] || (ov == bv[rt][e] && oi < bi[rt][e])) {
                    bv[rt][e] = ov; bi[rt][e] = oi; bg[rt][e] = og;
                }
            }
    }

    // pass 2: sum of exp(s - m_row) over this wave's 64 cols
    float ps[2][4];
    #pragma unroll
    for (int rt = 0; rt < 2; ++rt)
        #pragma unroll
        for (int e = 0; e < 4; ++e) {
            float s = 0.f;
            #pragma unroll
            for (int nt = 0; nt < 4; ++nt) s += expf(sv[rt][nt][e] - bv[rt][e]);
            ps[rt][e] = s;
        }
    #pragma unroll
    for (int msk = 1; msk <= 8; msk <<= 1)
        #pragma unroll
        for (int rt = 0; rt < 2; ++rt)
            #pragma unroll
            for (int e = 0; e < 4; ++e)
                ps[rt][e] += __shfl_xor(ps[rt][e], msk, 64);

    if (l15 == 0) {
        #pragma unroll
        for (int rt = 0; rt < 2; ++rt)
            #pragma unroll
            for (int e = 0; e < 4; ++e) {
                int r = rt * 16 + lg * 4 + e;
                red_m[w][r] = bv[rt][e];
                red_s[w][r] = ps[rt][e];
                red_bv[w][r] = bv[rt][e];
                red_bi[w][r] = bi[rt][e];
                red_bg[w][r] = bg[rt][e];
            }
    }
    __syncthreads();

    // combine the two waves -> lse per row
    float lse[2][4];
    #pragma unroll
    for (int rt = 0; rt < 2; ++rt)
        #pragma unroll
        for (int e = 0; e < 4; ++e) {
            int r = rt * 16 + lg * 4 + e;
            float m0 = red_m[0][r], m1 = red_m[1][r];
            float M = fmaxf(m0, m1);
            float S = red_s[0][r] * expf(m0 - M) + red_s[1][r] * expf(m1 - M);
            lse[rt][e] = logf(S) + M;
        }

    const float LOGC = -18.420680743952367f;  // ln(1e-8)
    #pragma unroll
    for (int rt = 0; rt < 2; ++rt)
        #pragma unroll
        for (int nt = 0; nt < 4; ++nt)
            #pragma unroll
            for (int e = 0; e < 4; ++e) {
                int r = rt * 16 + lg * 4 + e;
                int col = w * 64 + nt * 16 + l15;
                out[(size_t)(b0 + r) * TK + col] =
                    fmaxf(sv[rt][nt][e] - lse[rt][e], LOGC);
            }

    if (w == 0 && l15 == 0) {
        #pragma unroll
        for (int rt = 0; rt < 2; ++rt)
            #pragma unroll
            for (int e = 0; e < 4; ++e) {
                int r = rt * 16 + lg * 4 + e;
                float v0 = red_bv[0][r], v1 = red_bv[1][r];
                int i0 = red_bi[0][r], i1 = red_bi[1][r];
                float g0 = red_bg[0][r], g1 = red_bg[1][r];
                bool takeL = (v0 > v1) || (v0 == v1 && i0 < i1);
                int ki = takeL ? i0 : i1;
                float gg = takeL ? g0 : g1;
                out[(size_t)TB * TK + b0 + r] = sqrtf(fmaxf(gg + ebuf[ki], 0.f));
            }
    }
}

// ---------------------------------------------------------------------------
extern "C" void kernel_launch(void* const* d_in, const int* in_sizes, int n_in,
                              void* d_out, int out_size, void* d_ws, size_t ws_size,
                              hipStream_t stream) {
    const float* x  = (const float*)d_in[0];
    const float* C  = (const float*)d_in[1];
    const float* Dm = (const float*)d_in[2];
    float* out = (float*)d_out;

    _Float16* Wt = (_Float16*)d_ws;                                   // 256 KB
    float* off   = (float*)((char*)d_ws + (size_t)TK * KAUG * 2);     // 512 B
    float* ebuf  = off + TK;                                          // 512 B

    prep_kernel<<<TK, 64, 0, stream>>>(C, Dm, Wt, off, ebuf);
    gmm_kernel<<<NBLK, 128, 0, stream>>>(x, Wt, off, ebuf, out);
}

// Round 13
// 25.101 us; speedup vs baseline: 3.4158x; 3.4158x over previous
//
#include <hip/hip_runtime.h>
#include <math.h>

#define TB 2048
#define TK 128
#define TD 512
#define BR 16            // rows per block
#define NBLK (TB / BR)   // 128
#define KAUG 1024        // K' = 2*TD :  [0,512) -> 1/a ,  [512,1024) -> -2c/a
#define XSTR 1032        // XA row stride in halves (16B pad)

typedef _Float16 half8 __attribute__((ext_vector_type(8)));
typedef _Float16 half4 __attribute__((ext_vector_type(4)));
typedef float f32x4 __attribute__((ext_vector_type(4)));

// ws layout: Wt f16[128][1024] (256 KB) ; off f32[128] ; ebuf f32[128]

// ---------------------------------------------------------------------------
// Prep: Wt[k][d] = 1/a, Wt[k][512+d] = -2c/a   (a = |D|+eps, f16)
//       off[k] = -0.5*(e_k + sum log a),  ebuf[k] = e_k = sum c^2/a
// ---------------------------------------------------------------------------
__global__ __launch_bounds__(64) void prep_kernel(const float* __restrict__ C,
        const float* __restrict__ Dm, _Float16* __restrict__ Wt,
        float* __restrict__ off, float* __restrict__ ebuf) {
    const int k = blockIdx.x, lane = threadIdx.x;
    float esum = 0.f, lsum = 0.f;
    #pragma unroll
    for (int i = 0; i < 8; ++i) {
        int d = i * 64 + lane;
        float a = fabsf(Dm[k * TD + d]) + 1e-8f;
        float ia = 1.0f / a;
        float c = C[k * TD + d];
        float cia = c * ia;
        esum += c * cia;
        lsum += logf(a);
        Wt[(size_t)k * KAUG + d] = (_Float16)ia;
        Wt[(size_t)k * KAUG + TD + d] = (_Float16)(-2.0f * cia);
    }
    #pragma unroll
    for (int m = 32; m >= 1; m >>= 1) {
        esum += __shfl_xor(esum, m, 64);
        lsum += __shfl_xor(lsum, m, 64);
    }
    if (lane == 0) { off[k] = -0.5f * (esum + lsum); ebuf[k] = esum; }
}

// ---------------------------------------------------------------------------
// Main: 128 blocks x 512 thr (8 waves). Block = 16 rows x 128 k, full K'.
// Wave w owns cols [w*16, w*16+16): 32 MFMA (16x16x32_f16) over K'=1024,
// B-frags streamed from global (L2-hot), A staged once in LDS.
// Epilogue: per-wave softmax partials -> 2KB LDS -> combine -> resp + dist.
// ---------------------------------------------------------------------------
__global__ __launch_bounds__(512) void gmm_kernel(const float* __restrict__ x,
        const _Float16* __restrict__ Wt, const float* __restrict__ off,
        const float* __restrict__ ebuf, float* __restrict__ out) {
    __shared__ _Float16 XA[BR][XSTR];   // 33 KB: [row][k']  (x^2 | x)
    __shared__ float red_m[8][BR];
    __shared__ float red_s[8][BR];
    __shared__ float red_g[8][BR];
    __shared__ int   red_i[8][BR];

    const int tid = threadIdx.x;
    const int l = tid & 63;
    const int w = tid >> 6;
    const int l15 = l & 15;
    const int lg = l >> 4;
    const int b0 = blockIdx.x * BR;

    // ---- stage XA: 16 rows x 512 f32 -> f16 (x^2 at [d], x at [512+d]) ----
    #pragma unroll
    for (int i = 0; i < 4; ++i) {
        int f = tid + i * 512;          // 0..2047
        int row = f >> 7;               // 0..15
        int d0 = (f & 127) * 4;         // 0..508
        float4 v = *reinterpret_cast<const float4*>(&x[(size_t)(b0 + row) * TD + d0]);
        half4 hs, hi;
        hs[0] = (_Float16)(v.x * v.x); hs[1] = (_Float16)(v.y * v.y);
        hs[2] = (_Float16)(v.z * v.z); hs[3] = (_Float16)(v.w * v.w);
        hi[0] = (_Float16)v.x; hi[1] = (_Float16)v.y;
        hi[2] = (_Float16)v.z; hi[3] = (_Float16)v.w;
        *reinterpret_cast<half4*>(&XA[row][d0]) = hs;
        *reinterpret_cast<half4*>(&XA[row][TD + d0]) = hi;
    }
    __syncthreads();

    // ---- GEMM: this lane's B col-row ----
    const int col = w * 16 + l15;
    const _Float16* wrow = Wt + (size_t)col * KAUG;

    f32x4 acc0 = (f32x4){0.f, 0.f, 0.f, 0.f};
    f32x4 acc1 = (f32x4){0.f, 0.f, 0.f, 0.f};

    #pragma unroll 4
    for (int ks = 0; ks < 32; ks += 2) {
        int ko0 = ks * 32 + lg * 8;
        int ko1 = ko0 + 32;
        half8 a0 = *reinterpret_cast<const half8*>(&XA[l15][ko0]);
        half8 b0 = *reinterpret_cast<const half8*>(&wrow[ko0]);
        half8 a1 = *reinterpret_cast<const half8*>(&XA[l15][ko1]);
        half8 b1 = *reinterpret_cast<const half8*>(&wrow[ko1]);
        acc0 = __builtin_amdgcn_mfma_f32_16x16x32_f16(a0, b0, acc0, 0, 0, 0);
        acc1 = __builtin_amdgcn_mfma_f32_16x16x32_f16(a1, b1, acc1, 0, 0, 0);
    }
    f32x4 acc = acc0 + acc1;   // gemm = sum x^2/a - 2cx/a  (rows lg*4+e, col)

    // ---- epilogue: per-wave (16 cols) softmax partials ----
    const float offc = off[col];
    float sv[4], bv[4], bg[4], ps[4];
    int bi[4];
    #pragma unroll
    for (int e = 0; e < 4; ++e) {
        sv[e] = fmaf(-0.5f, acc[e], offc);
        bv[e] = sv[e]; bi[e] = col; bg[e] = acc[e];
    }
    #pragma unroll
    for (int msk = 1; msk <= 8; msk <<= 1) {
        #pragma unroll
        for (int e = 0; e < 4; ++e) {
            float ov = __shfl_xor(bv[e], msk, 64);
            int   oi = __shfl_xor(bi[e], msk, 64);
            float og = __shfl_xor(bg[e], msk, 64);
            if (ov > bv[e] || (ov == bv[e] && oi < bi[e])) {
                bv[e] = ov; bi[e] = oi; bg[e] = og;
            }
        }
    }
    #pragma unroll
    for (int e = 0; e < 4; ++e) ps[e] = expf(sv[e] - bv[e]);
    #pragma unroll
    for (int msk = 1; msk <= 8; msk <<= 1)
        #pragma unroll
        for (int e = 0; e < 4; ++e) ps[e] += __shfl_xor(ps[e], msk, 64);

    if (l15 == 0) {
        #pragma unroll
        for (int e = 0; e < 4; ++e) {
            int r = lg * 4 + e;
            red_m[w][r] = bv[e];
            red_s[w][r] = ps[e];
            red_i[w][r] = bi[e];
            red_g[w][r] = bg[e];
        }
    }
    __syncthreads();

    // ---- combine 8 waves per row -> lse; write resp ----
    const float LOGC = -18.420680743952367f;  // ln(1e-8)
    #pragma unroll
    for (int e = 0; e < 4; ++e) {
        int r = lg * 4 + e;
        float M = red_m[0][r];
        #pragma unroll
        for (int w2 = 1; w2 < 8; ++w2) M = fmaxf(M, red_m[w2][r]);
        float S = 0.f;
        #pragma unroll
        for (int w2 = 0; w2 < 8; ++w2) S += red_s[w2][r] * expf(red_m[w2][r] - M);
        float lse = logf(S) + M;
        out[(size_t)(b0 + r) * TK + col] = fmaxf(sv[e] - lse, LOGC);
    }

    // ---- dist: wave 0, lane-group leaders, global argmax over 8 waves ----
    if (w == 0 && l15 == 0) {
        #pragma unroll
        for (int e = 0; e < 4; ++e) {
            int r = lg * 4 + e;
            float v = red_m[0][r]; int ki = red_i[0][r]; float g = red_g[0][r];
            #pragma unroll
            for (int w2 = 1; w2 < 8; ++w2) {
                float v2 = red_m[w2][r]; int i2 = red_i[w2][r];
                if (v2 > v || (v2 == v && i2 < ki)) { v = v2; ki = i2; g = red_g[w2][r]; }
            }
            out[(size_t)TB * TK + b0 + r] = sqrtf(fmaxf(g + ebuf[ki], 0.f));
        }
    }
}

// ---------------------------------------------------------------------------
extern "C" void kernel_launch(void* const* d_in, const int* in_sizes, int n_in,
                              void* d_out, int out_size, void* d_ws, size_t ws_size,
                              hipStream_t stream) {
    const float* x  = (const float*)d_in[0];
    const float* C  = (const float*)d_in[1];
    const float* Dm = (const float*)d_in[2];
    float* out = (float*)d_out;

    _Float16* Wt = (_Float16*)d_ws;                                   // 256 KB
    float* off   = (float*)((char*)d_ws + (size_t)TK * KAUG * 2);     // 512 B
    float* ebuf  = off + TK;                                          // 512 B

    prep_kernel<<<TK, 64, 0, stream>>>(C, Dm, Wt, off, ebuf);
    gmm_kernel<<<NBLK, 512, 0, stream>>>(x, Wt, off, ebuf, out);
}